// Round 4
// baseline (459.456 us; speedup 1.0000x reference)
//
#include <hip/hip_runtime.h>

// Problem constants
#define BD   16
#define LQ   512
#define LK   4096
#define DM   128

typedef __attribute__((ext_vector_type(8))) short  short8;
typedef __attribute__((ext_vector_type(4))) float  f32x4;
typedef __attribute__((ext_vector_type(4))) int    i32x4;
typedef __attribute__((ext_vector_type(4))) unsigned short u16x4;

// ws layout in units of unsigned short (bf16 elements)
#define WQT_HI_S 0
#define WQT_LO_S 16384
#define WKT_HI_S 32768
#define WKT_LO_S 49152
#define QHI_S    65536
#define QLO_S    (QHI_S + BD * LQ * DM)      // 1,114,112
#define KHI_S    (QLO_S + BD * LQ * DM)      // 2,162,688
#define KLO_S    (KHI_S + BD * LK * DM)      // 10,551,296
#define ROWSUM_S (KLO_S + BD * LK * DM)      // 18,939,904 (floats live here)

static __device__ __forceinline__ unsigned short bf16_rne(float x) {
    union { float f; unsigned int u; } v; v.f = x;
    unsigned int u = v.u;
    u += 0x7FFFu + ((u >> 16) & 1u);
    return (unsigned short)(u >> 16);
}
static __device__ __forceinline__ float bf16_f32(unsigned short h) {
    union { unsigned int u; float f; } v; v.u = ((unsigned int)h) << 16;
    return v.f;
}

// Fragment-major offset for element (row, col) of a [R][128] bf16 plane,
// tiled in 16-row MFMA tiles. Reader (lane l, tile T, k-step s) sees
// offset T*2048 + s*512 + l*8 -> contiguous 1KB per (T,s) wave load.
static __device__ __forceinline__ int frag_off(int row, int col) {
    return ((row >> 4) << 11) + ((col >> 5) << 9) + (((col >> 3) & 3) << 7)
         + ((row & 15) << 3) + (col & 7);
}

// unnormalized softmax numerator: exp(C1 * tanh(x)), C1 = 10/sqrt(128)
static __device__ __forceinline__ float score_exp(float x) {
    const float C1 = 0.8838834764831844f;
    float e = __expf(2.0f * fabsf(x));                 // e^{2|x|}, inf-safe
    float th = 1.0f - 2.0f * __builtin_amdgcn_rcpf(e + 1.0f);
    return __expf(C1 * copysignf(th, x));              // arg in [-.884,.884]
}

// ---------------- kernel 1: Wq/Wk -> transposed, hi/lo, fragment-major ------
__global__ void setup_wt(const float* __restrict__ Wq, const float* __restrict__ Wk,
                         unsigned short* __restrict__ ws, float* __restrict__ rowsum) {
    int bx = blockIdx.x;                  // 64 blocks
    int mat = bx >> 5, chunk = bx & 31;
    const float* W = mat ? Wk : Wq;
    unsigned short* hi = ws + (mat ? WKT_HI_S : WQT_HI_S);
    unsigned short* lo = ws + (mat ? WKT_LO_S : WQT_LO_S);
    #pragma unroll
    for (int i = 0; i < 2; ++i) {
        int idx = chunk * 512 + i * 256 + threadIdx.x;   // 16384 per matrix
        int d = idx >> 7, e = idx & 127;
        float x = W[idx];                 // W[d][e]; wt plane is [e][d]
        unsigned short h = bf16_rne(x);
        unsigned short l = bf16_rne(x - bf16_f32(h));
        int off = frag_off(e, d);
        hi[off] = h;
        lo[off] = l;
    }
    int gtid = bx * 256 + threadIdx.x;
    if (gtid < BD * LQ) rowsum[gtid] = 0.0f;
}

// ---------------- kernel 2: projections, LDS-staged, fragment-major out -----
__global__ __launch_bounds__(256) void proj_kernel(
        const float* __restrict__ query, const float* __restrict__ key,
        const float* __restrict__ bq, const float* __restrict__ bk,
        unsigned short* __restrict__ ws) {
    __shared__ float tile[64 * 128];      // 32 KB, XOR-swizzled 32B granules
    const int tid = threadIdx.x;
    const int wave = tid >> 6, lane = tid & 63;
    const int r = lane & 15, g = lane >> 4;
    const int rt0 = blockIdx.x * 4;       // 1152 blocks x 4 rowtiles
    const bool isq = rt0 < 512;
    const float* src  = isq ? query : key;
    const float* bias = isq ? bq : bk;
    const unsigned short* wthi = ws + (isq ? WQT_HI_S : WKT_HI_S);
    const unsigned short* wtlo = ws + (isq ? WQT_LO_S : WKT_LO_S);
    unsigned short* ohi = ws + (isq ? QHI_S : KHI_S);
    unsigned short* olo = ws + (isq ? QLO_S : KLO_S);
    const int R0 = (isq ? rt0 : rt0 - 512) * 16;   // row base in q- or k-space

    {   // coalesced stage: 64 rows x 128 f32
        const f32x4* s4 = (const f32x4*)(src + (size_t)R0 * DM);
        char* tb = (char*)tile;
        #pragma unroll
        for (int u = 0; u < 8; ++u) {
            int idx = u * 256 + tid;
            int row = idx >> 5, c4 = idx & 31;
            int boff = (row << 9) + ((c4 << 4) ^ ((row & 7) << 5));
            *(f32x4*)(tb + boff) = s4[idx];
        }
    }
    __syncthreads();

    // build B fragments for this wave's 16 rows
    const int lrow = wave * 16 + r;
    short8 bh[4], bl[4];
    {
        const char* tb = (const char*)tile;
        const int xo = (lrow & 7) << 5;
        #pragma unroll
        for (int s = 0; s < 4; ++s) {
            int cb = (s << 7) + (g << 5);
            f32x4 x0 = *(const f32x4*)(tb + (lrow << 9) + (cb ^ xo));
            f32x4 x1 = *(const f32x4*)(tb + (lrow << 9) + ((cb ^ xo) + 16));
            #pragma unroll
            for (int j = 0; j < 8; ++j) {
                float x = (j < 4) ? x0[j] : x1[j - 4];
                unsigned short h = bf16_rne(x);
                bh[s][j] = (short)h;
                bl[s][j] = (short)bf16_rne(x - bf16_f32(h));
            }
        }
    }

    f32x4 acc[8];
    #pragma unroll
    for (int t = 0; t < 8; ++t) acc[t] = (f32x4){0.f, 0.f, 0.f, 0.f};

    #pragma unroll
    for (int s = 0; s < 4; ++s) {
        #pragma unroll
        for (int t = 0; t < 8; ++t) {
            short8 ah = *(const short8*)(wthi + t * 2048 + s * 512 + lane * 8);
            short8 al = *(const short8*)(wtlo + t * 2048 + s * 512 + lane * 8);
            acc[t] = __builtin_amdgcn_mfma_f32_16x16x32_bf16(ah, bh[s], acc[t], 0, 0, 0);
            acc[t] = __builtin_amdgcn_mfma_f32_16x16x32_bf16(ah, bl[s], acc[t], 0, 0, 0);
            acc[t] = __builtin_amdgcn_mfma_f32_16x16x32_bf16(al, bh[s], acc[t], 0, 0, 0);
        }
    }

    const int grow = R0 + lrow;
    const int b   = isq ? (grow >> 9)  : (grow >> 12);
    const int inb = isq ? (grow & 511) : (grow & 4095);
    unsigned short* hp = ohi + (size_t)b * (isq ? LQ * DM : LK * DM);
    unsigned short* lp = olo + (size_t)b * (isq ? LQ * DM : LK * DM);
    #pragma unroll
    for (int t = 0; t < 8; ++t) {
        int e0 = t * 16 + g * 4;
        f32x4 bv = *(const f32x4*)(bias + e0);
        u16x4 hs, ls;
        #pragma unroll
        for (int rr = 0; rr < 4; ++rr) {
            float v = acc[t][rr] + bv[rr];
            unsigned short h = bf16_rne(v);
            hs[rr] = h;
            ls[rr] = bf16_rne(v - bf16_f32(h));
        }
        int off = frag_off(inb, e0);
        *(u16x4*)(hp + off) = hs;
        *(u16x4*)(lp + off) = ls;
    }
}

// ---------------- kernel 3a: row sums of exp(clip(score)) -------------------
// 2048 wgs x 256 thr. Block = (b, 32 q-rows, k-eighth=512); wave owns 128 k.
// No p stores. Mask loaded with CACHING loads so it stays L3-resident for 3b.
__global__ __launch_bounds__(256, 4) void score_sum(
        const int* __restrict__ mask,
        const unsigned short* __restrict__ ws, float* __restrict__ rowsum) {
    const int wg = blockIdx.x;                 // 2048
    const int swz = (wg & 7) * 256 + (wg >> 3);
    const int qt2 = swz & 15;
    const int pr  = swz >> 4;                  // (b, ke)
    const int ke  = pr & 7;
    const int b   = pr >> 3;
    const int tid = threadIdx.x;
    const int wave = tid >> 6, lane = tid & 63;
    const int r = lane & 15, g = lane >> 4;
    const int kbase = ke * 512 + wave * 128;

    const unsigned short* qhi = ws + QHI_S + b * (LQ * DM);
    const unsigned short* qlo = ws + QLO_S + b * (LQ * DM);
    const unsigned short* khi = ws + KHI_S + (size_t)b * (LK * DM);
    const unsigned short* klo = ws + KLO_S + (size_t)b * (LK * DM);

    short8 qh[2][4], ql[2][4];
    #pragma unroll
    for (int h = 0; h < 2; ++h) {
        #pragma unroll
        for (int s = 0; s < 4; ++s) {
            int off = (qt2 * 2 + h) * 2048 + s * 512 + lane * 8;
            qh[h][s] = *(const short8*)(qhi + off);
            ql[h][s] = *(const short8*)(qlo + off);
        }
    }

    const int qrow0 = qt2 * 32 + r;
    const size_t base0 = (size_t)(b * LQ + qrow0) * LK + kbase + g * 4;
    const int* mrow0 = mask + base0;
    const int* mrow1 = mrow0 + 16 * LK;

    float ps0 = 0.f, ps1 = 0.f;
    #pragma unroll
    for (int TT = 0; TT < 2; ++TT) {
        i32x4 m0[4], m1[4];
        #pragma unroll
        for (int u = 0; u < 4; ++u) {          // caching loads: seed L3 for 3b
            m0[u] = *(const i32x4*)(mrow0 + (TT * 4 + u) * 16);
            m1[u] = *(const i32x4*)(mrow1 + (TT * 4 + u) * 16);
        }
        #pragma unroll
        for (int u = 0; u < 4; ++u) {
            const int T = ke * 32 + wave * 8 + TT * 4 + u;
            const unsigned short* khf = khi + T * 2048;
            const unsigned short* klf = klo + T * 2048;
            f32x4 a0 = (f32x4){0.f, 0.f, 0.f, 0.f};
            f32x4 a1 = (f32x4){0.f, 0.f, 0.f, 0.f};
            #pragma unroll
            for (int s = 0; s < 4; ++s) {
                short8 ah = *(const short8*)(khf + s * 512 + lane * 8);
                short8 al = *(const short8*)(klf + s * 512 + lane * 8);
                a0 = __builtin_amdgcn_mfma_f32_16x16x32_bf16(ah, qh[0][s], a0, 0, 0, 0);
                a1 = __builtin_amdgcn_mfma_f32_16x16x32_bf16(ah, qh[1][s], a1, 0, 0, 0);
                a0 = __builtin_amdgcn_mfma_f32_16x16x32_bf16(ah, ql[0][s], a0, 0, 0, 0);
                a1 = __builtin_amdgcn_mfma_f32_16x16x32_bf16(ah, ql[1][s], a1, 0, 0, 0);
                a0 = __builtin_amdgcn_mfma_f32_16x16x32_bf16(al, qh[0][s], a0, 0, 0, 0);
                a1 = __builtin_amdgcn_mfma_f32_16x16x32_bf16(al, qh[1][s], a1, 0, 0, 0);
            }
            #pragma unroll
            for (int rr = 0; rr < 4; ++rr) {
                float p0 = score_exp(a0[rr]);
                ps0 += (m0[u][rr] != 0) ? p0 : 0.0f;
                float p1 = score_exp(a1[rr]);
                ps1 += (m1[u][rr] != 0) ? p1 : 0.0f;
            }
        }
    }

    ps0 += __shfl_xor(ps0, 16, 64); ps0 += __shfl_xor(ps0, 32, 64);
    ps1 += __shfl_xor(ps1, 16, 64); ps1 += __shfl_xor(ps1, 32, 64);
    __shared__ float rs[32];
    if (tid < 32) rs[tid] = 0.f;
    __syncthreads();
    if (lane < 16) { atomicAdd(&rs[r], ps0); atomicAdd(&rs[16 + r], ps1); }
    __syncthreads();
    if (tid < 32) atomicAdd(rowsum + b * LQ + qt2 * 32 + tid, rs[tid]);
}

// ---------------- kernel 3b: recompute, normalize, NT-store out -------------
__global__ __launch_bounds__(256, 4) void score_write(
        const int* __restrict__ mask, float* __restrict__ out,
        const unsigned short* __restrict__ ws, const float* __restrict__ rowsum) {
    const int wg = blockIdx.x;                 // 2048
    const int swz = (wg & 7) * 256 + (wg >> 3);
    const int qt2 = swz & 15;
    const int pr  = swz >> 4;
    const int ke  = pr & 7;
    const int b   = pr >> 3;
    const int tid = threadIdx.x;
    const int wave = tid >> 6, lane = tid & 63;
    const int r = lane & 15, g = lane >> 4;
    const int kbase = ke * 512 + wave * 128;

    const unsigned short* qhi = ws + QHI_S + b * (LQ * DM);
    const unsigned short* qlo = ws + QLO_S + b * (LQ * DM);
    const unsigned short* khi = ws + KHI_S + (size_t)b * (LK * DM);
    const unsigned short* klo = ws + KLO_S + (size_t)b * (LK * DM);

    short8 qh[2][4], ql[2][4];
    #pragma unroll
    for (int h = 0; h < 2; ++h) {
        #pragma unroll
        for (int s = 0; s < 4; ++s) {
            int off = (qt2 * 2 + h) * 2048 + s * 512 + lane * 8;
            qh[h][s] = *(const short8*)(qhi + off);
            ql[h][s] = *(const short8*)(qlo + off);
        }
    }

    const int qrow0 = qt2 * 32 + r;
    const float rinv0 = 1.0f / rowsum[b * LQ + qrow0];
    const float rinv1 = 1.0f / rowsum[b * LQ + qrow0 + 16];
    const size_t base0 = (size_t)(b * LQ + qrow0) * LK + kbase + g * 4;
    const int* mrow0 = mask + base0;
    const int* mrow1 = mrow0 + 16 * LK;
    float*     orow0 = out + base0;
    float*     orow1 = orow0 + 16 * LK;

    #pragma unroll
    for (int TT = 0; TT < 2; ++TT) {
        i32x4 m0[4], m1[4];
        #pragma unroll
        for (int u = 0; u < 4; ++u) {          // last use: NT loads
            m0[u] = __builtin_nontemporal_load((const i32x4*)(mrow0 + (TT * 4 + u) * 16));
            m1[u] = __builtin_nontemporal_load((const i32x4*)(mrow1 + (TT * 4 + u) * 16));
        }
        #pragma unroll
        for (int u = 0; u < 4; ++u) {
            const int T = ke * 32 + wave * 8 + TT * 4 + u;
            const unsigned short* khf = khi + T * 2048;
            const unsigned short* klf = klo + T * 2048;
            f32x4 a0 = (f32x4){0.f, 0.f, 0.f, 0.f};
            f32x4 a1 = (f32x4){0.f, 0.f, 0.f, 0.f};
            #pragma unroll
            for (int s = 0; s < 4; ++s) {
                short8 ah = *(const short8*)(khf + s * 512 + lane * 8);
                short8 al = *(const short8*)(klf + s * 512 + lane * 8);
                a0 = __builtin_amdgcn_mfma_f32_16x16x32_bf16(ah, qh[0][s], a0, 0, 0, 0);
                a1 = __builtin_amdgcn_mfma_f32_16x16x32_bf16(ah, qh[1][s], a1, 0, 0, 0);
                a0 = __builtin_amdgcn_mfma_f32_16x16x32_bf16(ah, ql[0][s], a0, 0, 0, 0);
                a1 = __builtin_amdgcn_mfma_f32_16x16x32_bf16(ah, ql[1][s], a1, 0, 0, 0);
                a0 = __builtin_amdgcn_mfma_f32_16x16x32_bf16(al, qh[0][s], a0, 0, 0, 0);
                a1 = __builtin_amdgcn_mfma_f32_16x16x32_bf16(al, qh[1][s], a1, 0, 0, 0);
            }
            f32x4 o0, o1;
            #pragma unroll
            for (int rr = 0; rr < 4; ++rr) {
                float p0 = score_exp(a0[rr]);
                o0[rr] = ((m0[u][rr] != 0) ? p0 : 0.0f) * rinv0;
                float p1 = score_exp(a1[rr]);
                o1[rr] = ((m1[u][rr] != 0) ? p1 : 0.0f) * rinv1;
            }
            __builtin_nontemporal_store(o0, (f32x4*)(orow0 + (TT * 4 + u) * 16));
            __builtin_nontemporal_store(o1, (f32x4*)(orow1 + (TT * 4 + u) * 16));
        }
    }
}

extern "C" void kernel_launch(void* const* d_in, const int* in_sizes, int n_in,
                              void* d_out, int out_size, void* d_ws, size_t ws_size,
                              hipStream_t stream) {
    const float* query = (const float*)d_in[0];
    const float* key   = (const float*)d_in[1];
    const int*   mask  = (const int*)d_in[2];
    const float* Wq    = (const float*)d_in[3];
    const float* bq    = (const float*)d_in[4];
    const float* Wk    = (const float*)d_in[5];
    const float* bk    = (const float*)d_in[6];
    float* out = (float*)d_out;
    unsigned short* ws = (unsigned short*)d_ws;
    float* rowsum = (float*)(ws + ROWSUM_S);

    setup_wt<<<64, 256, 0, stream>>>(Wq, Wk, ws, rowsum);
    proj_kernel<<<(512 + 4096) / 4, 256, 0, stream>>>(query, key, bq, bk, ws);
    score_sum<<<2048, 256, 0, stream>>>(mask, ws, rowsum);
    score_write<<<2048, 256, 0, stream>>>(mask, out, ws, rowsum);
}

// Round 7
// 364.916 us; speedup vs baseline: 1.2591x; 1.2591x over previous
//
#include <hip/hip_runtime.h>

// Problem constants
#define BD   16
#define LQ   512
#define LK   4096
#define DM   128

typedef __attribute__((ext_vector_type(8))) short  short8;
typedef __attribute__((ext_vector_type(4))) float  f32x4;
typedef __attribute__((ext_vector_type(4))) int    i32x4;
typedef __attribute__((ext_vector_type(4))) unsigned short u16x4;
typedef _Float16 half4 __attribute__((ext_vector_type(4)));

// ws layout in units of unsigned short (bf16 elements)
#define WQT_HI_S 0
#define WQT_LO_S 16384
#define WKT_HI_S 32768
#define WKT_LO_S 49152
#define QHI_S    65536
#define QLO_S    (QHI_S + BD * LQ * DM)      // 1,114,112
#define KHI_S    (QLO_S + BD * LQ * DM)      // 2,162,688
#define KLO_S    (KHI_S + BD * LK * DM)      // 10,551,296

static __device__ __forceinline__ unsigned short bf16_rne(float x) {
    union { float f; unsigned int u; } v; v.f = x;
    unsigned int u = v.u;
    u += 0x7FFFu + ((u >> 16) & 1u);
    return (unsigned short)(u >> 16);
}
static __device__ __forceinline__ float bf16_f32(unsigned short h) {
    union { unsigned int u; float f; } v; v.u = ((unsigned int)h) << 16;
    return v.f;
}

// Fragment-major offset for element (row, col) of a [R][128] bf16 plane,
// tiled in 16-row MFMA tiles. Reader (lane l, tile T, k-step s) sees
// offset T*2048 + s*512 + l*8 -> contiguous 1KB per (T,s) wave load.
static __device__ __forceinline__ int frag_off(int row, int col) {
    return ((row >> 4) << 11) + ((col >> 5) << 9) + (((col >> 3) & 3) << 7)
         + ((row & 15) << 3) + (col & 7);
}

// unnormalized softmax numerator: exp(C1 * tanh(x)), C1 = 10/sqrt(128)
static __device__ __forceinline__ float score_exp(float x) {
    const float C1 = 0.8838834764831844f;
    float e = __expf(2.0f * fabsf(x));                 // e^{2|x|}, inf-safe
    float th = 1.0f - 2.0f * __builtin_amdgcn_rcpf(e + 1.0f);
    return __expf(C1 * copysignf(th, x));              // arg in [-.884,.884]
}

// ---------------- kernel 1: Wq/Wk -> transposed, hi/lo, fragment-major ------
__global__ void setup_wt(const float* __restrict__ Wq, const float* __restrict__ Wk,
                         unsigned short* __restrict__ ws) {
    int bx = blockIdx.x;                  // 64 blocks
    int mat = bx >> 5, chunk = bx & 31;
    const float* W = mat ? Wk : Wq;
    unsigned short* hi = ws + (mat ? WKT_HI_S : WQT_HI_S);
    unsigned short* lo = ws + (mat ? WKT_LO_S : WQT_LO_S);
    #pragma unroll
    for (int i = 0; i < 2; ++i) {
        int idx = chunk * 512 + i * 256 + threadIdx.x;   // 16384 per matrix
        int d = idx >> 7, e = idx & 127;
        float x = W[idx];                 // W[d][e]; wt plane is [e][d]
        unsigned short h = bf16_rne(x);
        unsigned short l = bf16_rne(x - bf16_f32(h));
        int off = frag_off(e, d);
        hi[off] = h;
        lo[off] = l;
    }
}

// ---------------- kernel 2: projections, LDS-staged, fragment-major out -----
__global__ __launch_bounds__(256) void proj_kernel(
        const float* __restrict__ query, const float* __restrict__ key,
        const float* __restrict__ bq, const float* __restrict__ bk,
        unsigned short* __restrict__ ws) {
    __shared__ float tile[64 * 128];      // 32 KB, XOR-swizzled 32B granules
    const int tid = threadIdx.x;
    const int wave = tid >> 6, lane = tid & 63;
    const int r = lane & 15, g = lane >> 4;
    const int rt0 = blockIdx.x * 4;       // 1152 blocks x 4 rowtiles
    const bool isq = rt0 < 512;
    const float* src  = isq ? query : key;
    const float* bias = isq ? bq : bk;
    const unsigned short* wthi = ws + (isq ? WQT_HI_S : WKT_HI_S);
    const unsigned short* wtlo = ws + (isq ? WQT_LO_S : WKT_LO_S);
    unsigned short* ohi = ws + (isq ? QHI_S : KHI_S);
    unsigned short* olo = ws + (isq ? QLO_S : KLO_S);
    const int R0 = (isq ? rt0 : rt0 - 512) * 16;   // row base in q- or k-space

    {   // coalesced stage: 64 rows x 128 f32
        const f32x4* s4 = (const f32x4*)(src + (size_t)R0 * DM);
        char* tb = (char*)tile;
        #pragma unroll
        for (int u = 0; u < 8; ++u) {
            int idx = u * 256 + tid;
            int row = idx >> 5, c4 = idx & 31;
            int boff = (row << 9) + ((c4 << 4) ^ ((row & 7) << 5));
            *(f32x4*)(tb + boff) = s4[idx];
        }
    }
    __syncthreads();

    // build B fragments for this wave's 16 rows
    const int lrow = wave * 16 + r;
    short8 bh[4], bl[4];
    {
        const char* tb = (const char*)tile;
        const int xo = (lrow & 7) << 5;
        #pragma unroll
        for (int s = 0; s < 4; ++s) {
            int cb = (s << 7) + (g << 5);
            f32x4 x0 = *(const f32x4*)(tb + (lrow << 9) + (cb ^ xo));
            f32x4 x1 = *(const f32x4*)(tb + (lrow << 9) + ((cb ^ xo) + 16));
            #pragma unroll
            for (int j = 0; j < 8; ++j) {
                float x = (j < 4) ? x0[j] : x1[j - 4];
                unsigned short h = bf16_rne(x);
                bh[s][j] = (short)h;
                bl[s][j] = (short)bf16_rne(x - bf16_f32(h));
            }
        }
    }

    f32x4 acc[8];
    #pragma unroll
    for (int t = 0; t < 8; ++t) acc[t] = (f32x4){0.f, 0.f, 0.f, 0.f};

    #pragma unroll
    for (int s = 0; s < 4; ++s) {
        #pragma unroll
        for (int t = 0; t < 8; ++t) {
            short8 ah = *(const short8*)(wthi + t * 2048 + s * 512 + lane * 8);
            short8 al = *(const short8*)(wtlo + t * 2048 + s * 512 + lane * 8);
            acc[t] = __builtin_amdgcn_mfma_f32_16x16x32_bf16(ah, bh[s], acc[t], 0, 0, 0);
            acc[t] = __builtin_amdgcn_mfma_f32_16x16x32_bf16(ah, bl[s], acc[t], 0, 0, 0);
            acc[t] = __builtin_amdgcn_mfma_f32_16x16x32_bf16(al, bh[s], acc[t], 0, 0, 0);
        }
    }

    const int grow = R0 + lrow;
    const int b   = isq ? (grow >> 9)  : (grow >> 12);
    const int inb = isq ? (grow & 511) : (grow & 4095);
    unsigned short* hp = ohi + (size_t)b * (isq ? LQ * DM : LK * DM);
    unsigned short* lp = olo + (size_t)b * (isq ? LQ * DM : LK * DM);
    #pragma unroll
    for (int t = 0; t < 8; ++t) {
        int e0 = t * 16 + g * 4;
        f32x4 bv = *(const f32x4*)(bias + e0);
        u16x4 hs, ls;
        #pragma unroll
        for (int rr = 0; rr < 4; ++rr) {
            float v = acc[t][rr] + bv[rr];
            unsigned short h = bf16_rne(v);
            hs[rr] = h;
            ls[rr] = bf16_rne(v - bf16_f32(h));
        }
        int off = frag_off(inb, e0);
        *(u16x4*)(hp + off) = hs;
        *(u16x4*)(lp + off) = ls;
    }
}

// ---------------- kernel 3: fused scores + softmax, p staged in LDS f16 -----
// 512 wgs x 512 thr. Block = (b, 16 q-rows) x ALL 4096 k; wave owns 512 k.
// Phase 1: MFMA -> tanh -> exp -> mask -> psum; p stored to LDS as f16
// (128 KB, XOR-swizzled to the b64 bank floor). One barrier combines the
// 8 per-wave rowsums. Phase 2: read own LDS, scale by 1/rowsum, REGULAR
// f32x4 stores (L2 merges the 64B/row chunks into full lines - round-4
// lesson: NT scatter stores = 2x write amplification).
__global__ __launch_bounds__(512, 2) void score_fused(
        const int* __restrict__ mask, float* __restrict__ out,
        const unsigned short* __restrict__ ws) {
    __shared__ _Float16 plds[16 * 4096];   // 128 KB
    __shared__ float red[8 * 16];

    const int wg = blockIdx.x;             // 512
    const int xcd = wg & 7, j = wg >> 3;   // 2 batches per XCD -> k L2-hot
    const int b  = xcd * 2 + (j & 1);
    const int qt = j >> 1;                 // 0..31
    const int tid = threadIdx.x;
    const int wave = tid >> 6, lane = tid & 63;
    const int r = lane & 15, g = lane >> 4;

    const unsigned short* qhi = ws + QHI_S + b * (LQ * DM);
    const unsigned short* qlo = ws + QLO_S + b * (LQ * DM);
    const unsigned short* khi = ws + KHI_S + (size_t)b * (LK * DM) + wave * (32 * 2048);
    const unsigned short* klo = ws + KLO_S + (size_t)b * (LK * DM) + wave * (32 * 2048);

    short8 qh[4], ql[4];
    #pragma unroll
    for (int s = 0; s < 4; ++s) {
        qh[s] = *(const short8*)(qhi + qt * 2048 + s * 512 + lane * 8);
        ql[s] = *(const short8*)(qlo + qt * 2048 + s * 512 + lane * 8);
    }

    const int row = qt * 16 + r;
    const size_t base = (size_t)(b * LQ + row) * LK + wave * 512 + g * 4;
    const int* mrow = mask + base;
    float*     orow = out + base;
    char* pb = (char*)plds;
    const int sw = (r & 15) << 3;          // byte-XOR swizzle, bits 3..6

    float psum = 0.f;
    #pragma unroll 2
    for (int t = 0; t < 32; ++t) {
        i32x4 mv = __builtin_nontemporal_load((const i32x4*)(mrow + t * 16));
        const unsigned short* khf = khi + t * 2048;
        const unsigned short* klf = klo + t * 2048;
        f32x4 a = (f32x4){0.f, 0.f, 0.f, 0.f};
        #pragma unroll
        for (int s = 0; s < 4; ++s) {
            short8 ah = *(const short8*)(khf + s * 512 + lane * 8);
            short8 al = *(const short8*)(klf + s * 512 + lane * 8);
            a = __builtin_amdgcn_mfma_f32_16x16x32_bf16(ah, qh[s], a, 0, 0, 0);
            a = __builtin_amdgcn_mfma_f32_16x16x32_bf16(ah, ql[s], a, 0, 0, 0);
            a = __builtin_amdgcn_mfma_f32_16x16x32_bf16(al, qh[s], a, 0, 0, 0);
        }
        half4 ph;
        #pragma unroll
        for (int rr = 0; rr < 4; ++rr) {
            float p = score_exp(a[rr]);
            p = (mv[rr] != 0) ? p : 0.0f;
            psum += p;
            ph[rr] = (_Float16)p;
        }
        int off = (wave * 1024 + t * 32 + g * 8) ^ sw;
        *(half4*)(pb + r * 8192 + off) = ph;
    }

    psum += __shfl_xor(psum, 16, 64);
    psum += __shfl_xor(psum, 32, 64);
    if (lane < 16) red[wave * 16 + lane] = psum;
    __syncthreads();
    float S = 0.f;
    #pragma unroll
    for (int w = 0; w < 8; ++w) S += red[w * 16 + r];
    const float rinv = 1.0f / S;

    #pragma unroll 2
    for (int t = 0; t < 32; ++t) {
        int off = (wave * 1024 + t * 32 + g * 8) ^ sw;
        half4 ph = *(const half4*)(pb + r * 8192 + off);
        f32x4 o = (f32x4){(float)ph[0] * rinv, (float)ph[1] * rinv,
                          (float)ph[2] * rinv, (float)ph[3] * rinv};
        *(f32x4*)(orow + t * 16) = o;      // regular store: L2 line-merge
    }
}

extern "C" void kernel_launch(void* const* d_in, const int* in_sizes, int n_in,
                              void* d_out, int out_size, void* d_ws, size_t ws_size,
                              hipStream_t stream) {
    const float* query = (const float*)d_in[0];
    const float* key   = (const float*)d_in[1];
    const int*   mask  = (const int*)d_in[2];
    const float* Wq    = (const float*)d_in[3];
    const float* bq    = (const float*)d_in[4];
    const float* Wk    = (const float*)d_in[5];
    const float* bk    = (const float*)d_in[6];
    float* out = (float*)d_out;
    unsigned short* ws = (unsigned short*)d_ws;

    setup_wt<<<64, 256, 0, stream>>>(Wq, Wk, ws);
    proj_kernel<<<(512 + 4096) / 4, 256, 0, stream>>>(query, key, bq, bk, ws);
    score_fused<<<512, 512, 0, stream>>>(mask, out, ws);
}